// Round 5
// baseline (252.206 us; speedup 1.0000x reference)
//
#include <hip/hip_runtime.h>
#include <math.h>

#define NEG_SLOPE 0.2f
#define SM_EPS 1e-16f

typedef short short8 __attribute__((ext_vector_type(8)));
typedef float floatx4 __attribute__((ext_vector_type(4)));

// ---------------- helpers ----------------

__device__ inline unsigned short f2bf(float x) {
    unsigned int u = __float_as_uint(x);
    unsigned int r = (u + 0x7FFFu + ((u >> 16) & 1u)) >> 16;
    return (unsigned short)r;
}

__device__ inline float bf2f(unsigned short h) {
    return __uint_as_float(((unsigned int)h) << 16);
}

__device__ inline float bflo(unsigned int u) { return __uint_as_float(u << 16); }
__device__ inline float bfhi(unsigned int u) { return __uint_as_float(u & 0xFFFF0000u); }

// async global->LDS 16B copy: LDS dst = wave-uniform base + lane*16
__device__ __forceinline__ void gl_lds16(const unsigned short* g, unsigned short* l) {
    __builtin_amdgcn_global_load_lds(
        (const __attribute__((address_space(1))) unsigned int*)(g),
        (__attribute__((address_space(3))) unsigned int*)(l), 16, 0, 0);
}

__device__ inline void get_edge(const int* __restrict__ srcA, const int* __restrict__ dstA,
                                int e, int E, int& s, int& d) {
    if (e < E) { s = srcA[e]; d = dstA[e]; }
    else { s = e - E; d = e - E; }   // self-loops appended after real edges
}

// ---------------- fused prep: deg histogram | x->bf16 | W1t | W2t ----------------

__global__ __launch_bounds__(256) void k_prep(const float* __restrict__ x,
                                              unsigned short* __restrict__ xb,
                                              const float* __restrict__ W1,
                                              unsigned short* __restrict__ w1t,
                                              const float* __restrict__ W2,
                                              unsigned short* __restrict__ w2bt,
                                              const int* __restrict__ dstA,
                                              int E, int Ep,
                                              int* __restrict__ deg,
                                              int nblk_deg, int nblk_x) {
    __shared__ float tile[32][33];
    int bx = blockIdx.x;
    int t = threadIdx.x;
    if (bx < nblk_deg) {
        int e = bx * 256 + t;
        if (e < Ep) {
            int d = (e < E) ? dstA[e] : (e - E);
            atomicAdd(&deg[d], 1);
        }
    } else if (bx < nblk_deg + nblk_x) {
        int i = ((bx - nblk_deg) * 256 + t) * 4;
        float4 v = *(const float4*)(x + i);
        ushort4 o;
        o.x = f2bf(v.x); o.y = f2bf(v.y); o.z = f2bf(v.z); o.w = f2bf(v.w);
        *(ushort4*)(xb + i) = o;
    } else if (bx < nblk_deg + nblk_x + 256) {
        int b = bx - nblk_deg - nblk_x;          // 0..255
        int kb = (b & 15) * 32;                  // k base
        int nb = (b >> 4) * 32;                  // n base
        int tx = t & 31, ty = t >> 5;            // 32x8
        #pragma unroll
        for (int i = 0; i < 32; i += 8)
            tile[ty + i][tx] = W1[(size_t)(kb + ty + i) * 512 + nb + tx];
        __syncthreads();
        #pragma unroll
        for (int i = 0; i < 32; i += 8)
            w1t[(size_t)(nb + ty + i) * 512 + kb + tx] = f2bf(tile[tx][ty + i]);
    } else {
        int i = (bx - nblk_deg - nblk_x - 256) * 256 + t;   // 0..16383
        int c = i >> 9, k = i & 511;
        w2bt[i] = f2bf(W2[k * 32 + c]);
    }
}

// ---------------- CSR build: fused single-pass scan ----------------
// 79 blocks << 256 CUs -> all co-resident -> device-scope flag barrier is safe.

__global__ __launch_bounds__(256) void k_scan_fused(const int* __restrict__ deg,
                                                    int* __restrict__ part,
                                                    int* __restrict__ done,
                                                    int* __restrict__ off,
                                                    int* __restrict__ cursor,
                                                    int N, int nblk) {
    __shared__ int sm[256];
    int bx = blockIdx.x, t = threadIdx.x;
    int i = bx * 256 + t;
    int v = (i < N) ? deg[i] : 0;
    sm[t] = v; __syncthreads();
    for (int o = 1; o < 256; o <<= 1) {
        int x = (t >= o) ? sm[t - o] : 0;
        __syncthreads();
        sm[t] += x;
        __syncthreads();
    }
    int incl_v = sm[t];
    if (t == 255) {
        part[bx] = sm[255];
        __threadfence();              // publish part before flag
        atomicAdd(done, 1);
    }
    if (t == 0) {
        while (atomicAdd(done, 0) < nblk) { }   // spin: all parts published
        __threadfence();
    }
    __syncthreads();
    int partial = 0;
    for (int j = t; j < bx; j += 256) partial += atomicAdd(&part[j], 0);
    sm[t] = partial; __syncthreads();
    for (int o = 128; o > 0; o >>= 1) {
        if (t < o) sm[t] += sm[t + o];
        __syncthreads();
    }
    int base = sm[0];
    if (i < N) {
        int vv = incl_v + base;       // inclusive scan value
        off[i + 1] = vv;
        cursor[i] = vv - v;
        if (i == 0) off[0] = 0;
    }
}

__global__ __launch_bounds__(256) void k_scatter(const int* __restrict__ srcA, const int* __restrict__ dstA,
                                                 int E, int Ep, int* __restrict__ cursor,
                                                 int* __restrict__ src_s) {
    int e = blockIdx.x * 256 + threadIdx.x;
    if (e >= Ep) return;
    int s, d; get_edge(srcA, dstA, e, E, s, d);
    int p = atomicAdd(&cursor[d], 1);
    src_s[p] = s;
}

// ---------------- GEMM1 (bf16 MFMA) + fused attn1 ----------------
// v5: BM=64, BN=128, BK=32, 4 waves (wave = 32x64, acc[2][4] = 32 AGPR).
// counted vmcnt(3) pipeline, both-sides XOR swizzle.
// attn dots HEAD-MAJOR: a_sd[h*N + r].

__global__ __launch_bounds__(256, 4) void k_gemm1_mfma(const unsigned short* __restrict__ A,
                                                       const unsigned short* __restrict__ Bt,
                                                       const float* __restrict__ att_s,
                                                       const float* __restrict__ att_d,
                                                       unsigned short* __restrict__ C,
                                                       float* __restrict__ a_sd,
                                                       float* __restrict__ a_dd, int M) {
    const int K = 512;
    __shared__ unsigned short As[2][64 * 32];    // 2 x 4 KB
    __shared__ unsigned short Bs[2][128 * 32];   // 2 x 8 KB
    int t = threadIdx.x;
    int lane = t & 63;
    int w = t >> 6;                  // 0..3
    int row0 = blockIdx.x * 64;
    int col0 = blockIdx.y * 128;
    int wm = (w >> 1) * 32, wn = (w & 1) * 64;
    int l15 = lane & 15, q = lane >> 4;

    int srl = lane >> 2;                              // row within 16-group
    int sgc = ((lane & 3) ^ ((lane >> 3) & 3)) * 8;   // swizzled src chunk (elements)

    floatx4 acc[2][4] = {};

    auto STAGE = [&](int buf, int k0) {
        gl_lds16(A  + (size_t)(row0 + w * 16 + srl) * K + k0 + sgc, &As[buf][(w * 16) * 32]);
        gl_lds16(Bt + (size_t)(col0 + w * 32 + srl) * K + k0 + sgc, &Bs[buf][(w * 32) * 32]);
        gl_lds16(Bt + (size_t)(col0 + w * 32 + 16 + srl) * K + k0 + sgc, &Bs[buf][(w * 32 + 16) * 32]);
    };

    STAGE(0, 0);
    asm volatile("s_waitcnt vmcnt(0)" ::: "memory");
    __builtin_amdgcn_s_barrier();

    int swz = (l15 >> 1) & 3;        // (row>>1)&3 for row = {wm|wn} + i*16 + l15
    int buf = 0;
    for (int k0 = 0; k0 < K; k0 += 32) {
        if (k0 + 32 < K) {
            STAGE(buf ^ 1, k0 + 32);                       // 3 loads in flight across barrier
            asm volatile("s_waitcnt vmcnt(3)" ::: "memory");
        } else {
            asm volatile("s_waitcnt vmcnt(0)" ::: "memory");
        }
        __builtin_amdgcn_s_barrier();
        __builtin_amdgcn_sched_barrier(0);
        short8 af[2], bfr[4];
        int sw = (q ^ swz) << 3;     // swizzled 16B chunk -> element offset
        #pragma unroll
        for (int i = 0; i < 2; ++i)
            af[i] = *(const short8*)(&As[buf][(wm + i * 16 + l15) * 32 + sw]);
        #pragma unroll
        for (int j = 0; j < 4; ++j)
            bfr[j] = *(const short8*)(&Bs[buf][(wn + j * 16 + l15) * 32 + sw]);
        #pragma unroll
        for (int i = 0; i < 2; ++i)
            #pragma unroll
            for (int j = 0; j < 4; ++j)
                acc[i][j] = __builtin_amdgcn_mfma_f32_16x16x32_bf16(af[i], bfr[j], acc[i][j], 0, 0, 0);
        asm volatile("s_waitcnt lgkmcnt(0)" ::: "memory");
        __builtin_amdgcn_sched_barrier(0);
        __builtin_amdgcn_s_barrier();
        buf ^= 1;
    }

    #pragma unroll
    for (int i = 0; i < 2; ++i) {
        #pragma unroll
        for (int p = 0; p < 4; ++p) {
            int r = row0 + wm + i * 16 + q * 4 + p;
            if (r < M) {
                #pragma unroll
                for (int j = 0; j < 4; ++j) {
                    int c = col0 + wn + j * 16 + l15;
                    C[(size_t)r * 512 + c] = f2bf(acc[i][j][p]);
                }
            }
        }
    }

    int hh = blockIdx.y * 2 + (w & 1);   // wave's wn half = one full 64-chan head
    float asr[4], adr[4];
    #pragma unroll
    for (int j = 0; j < 4; ++j) {
        asr[j] = att_s[hh * 64 + j * 16 + l15];
        adr[j] = att_d[hh * 64 + j * 16 + l15];
    }
    #pragma unroll
    for (int i = 0; i < 2; ++i) {
        #pragma unroll
        for (int p = 0; p < 4; ++p) {
            float ds = 0.f, dd = 0.f;
            #pragma unroll
            for (int j = 0; j < 4; ++j) {
                ds = fmaf(acc[i][j][p], asr[j], ds);
                dd = fmaf(acc[i][j][p], adr[j], dd);
            }
            #pragma unroll
            for (int mk = 1; mk <= 8; mk <<= 1) {
                ds += __shfl_xor(ds, mk);
                dd += __shfl_xor(dd, mk);
            }
            int r = row0 + wm + i * 16 + q * 4 + p;
            if (l15 == 0 && r < M) {
                a_sd[(size_t)hh * M + r] = ds;
                a_dd[(size_t)hh * M + r] = dd;
            }
        }
    }
}

// ---------------- layer-1 v3: wave-per-(node,head), 8-edge-parallel ----------------
// Was: lane-private walk (wave = 8 nodes x 1 head) -> wave time = max deg over 8
// nodes (~1.65x waste for Poisson(16)). Now: wave = 1 node x 1 head, lane =
// (edge-slot e8 = lane>>3, chan-group li = lane&7, 8 ch each). Wave time =
// ceil(deg/8); >=8 gathers in flight. Same bytes, same 128 B row-slice per edge,
// same XCD head affinity (h = bx & 7 -> per-XCD 2.56 MB slice).

__global__ __launch_bounds__(256) void k_l1(const unsigned short* __restrict__ xw,
                                            const float* __restrict__ a_s,
                                            const float* __restrict__ a_d,
                                            const int* __restrict__ off,
                                            const int* __restrict__ src_s,
                                            const float* __restrict__ bias,
                                            unsigned short* __restrict__ hout, int N) {
    int wid = threadIdx.x >> 6, lane = threadIdx.x & 63;
    int h = blockIdx.x & 7;
    int n = (blockIdx.x >> 3) * 4 + wid;      // 4 nodes (waves) per block
    if (n >= N) return;
    int e8 = lane >> 3;                        // edge slot 0..7
    int li = lane & 7;                         // channel group: 8 ch
    int p0 = off[n], p1 = off[n + 1];
    const float* ash = a_s + (size_t)h * N;
    float adv = a_d[(size_t)h * N + n];
    const size_t cbase = (size_t)h * 64 + (size_t)li * 8;

    float acc[8] = {};
    float s = 0.f;
    int p = p0;
    for (; p + 16 <= p1; p += 16) {            // 2 groups of 8 edges in flight
        int sA = src_s[p + e8];
        int sB = src_s[p + 8 + e8];
        const uint4 uA = *(const uint4*)(xw + (size_t)sA * 512 + cbase);
        const uint4 uB = *(const uint4*)(xw + (size_t)sB * 512 + cbase);
        float eA = ash[sA] + adv; eA = eA > 0.f ? eA : NEG_SLOPE * eA;
        float eB = ash[sB] + adv; eB = eB > 0.f ? eB : NEG_SLOPE * eB;
        float wA = __expf(eA);
        float wB = __expf(eB);
        s += wA + wB;
        acc[0] = fmaf(wA, bflo(uA.x), acc[0]); acc[1] = fmaf(wA, bfhi(uA.x), acc[1]);
        acc[2] = fmaf(wA, bflo(uA.y), acc[2]); acc[3] = fmaf(wA, bfhi(uA.y), acc[3]);
        acc[4] = fmaf(wA, bflo(uA.z), acc[4]); acc[5] = fmaf(wA, bfhi(uA.z), acc[5]);
        acc[6] = fmaf(wA, bflo(uA.w), acc[6]); acc[7] = fmaf(wA, bfhi(uA.w), acc[7]);
        acc[0] = fmaf(wB, bflo(uB.x), acc[0]); acc[1] = fmaf(wB, bfhi(uB.x), acc[1]);
        acc[2] = fmaf(wB, bflo(uB.y), acc[2]); acc[3] = fmaf(wB, bfhi(uB.y), acc[3]);
        acc[4] = fmaf(wB, bflo(uB.z), acc[4]); acc[5] = fmaf(wB, bfhi(uB.z), acc[5]);
        acc[6] = fmaf(wB, bflo(uB.w), acc[6]); acc[7] = fmaf(wB, bfhi(uB.w), acc[7]);
    }
    for (; p + 8 <= p1; p += 8) {
        int sA = src_s[p + e8];
        const uint4 uA = *(const uint4*)(xw + (size_t)sA * 512 + cbase);
        float eA = ash[sA] + adv; eA = eA > 0.f ? eA : NEG_SLOPE * eA;
        float wA = __expf(eA);
        s += wA;
        acc[0] = fmaf(wA, bflo(uA.x), acc[0]); acc[1] = fmaf(wA, bfhi(uA.x), acc[1]);
        acc[2] = fmaf(wA, bflo(uA.y), acc[2]); acc[3] = fmaf(wA, bfhi(uA.y), acc[3]);
        acc[4] = fmaf(wA, bflo(uA.z), acc[4]); acc[5] = fmaf(wA, bfhi(uA.z), acc[5]);
        acc[6] = fmaf(wA, bflo(uA.w), acc[6]); acc[7] = fmaf(wA, bfhi(uA.w), acc[7]);
    }
    if (p < p1) {                              // masked tail, <=7 edges
        int nb = p1 - p;
        bool val = e8 < nb;
        int sA = src_s[val ? p + e8 : p];
        const uint4 uA = *(const uint4*)(xw + (size_t)sA * 512 + cbase);
        float eA = ash[sA] + adv; eA = eA > 0.f ? eA : NEG_SLOPE * eA;
        float wA = val ? __expf(eA) : 0.f;
        s += wA;
        acc[0] = fmaf(wA, bflo(uA.x), acc[0]); acc[1] = fmaf(wA, bfhi(uA.x), acc[1]);
        acc[2] = fmaf(wA, bflo(uA.y), acc[2]); acc[3] = fmaf(wA, bfhi(uA.y), acc[3]);
        acc[4] = fmaf(wA, bflo(uA.z), acc[4]); acc[5] = fmaf(wA, bfhi(uA.z), acc[5]);
        acc[6] = fmaf(wA, bflo(uA.w), acc[6]); acc[7] = fmaf(wA, bfhi(uA.w), acc[7]);
    }

    // reduce across the 8 edge slots (lane bits 3..5), li preserved
    #pragma unroll
    for (int mk = 8; mk <= 32; mk <<= 1) {
        s += __shfl_xor(s, mk);
        #pragma unroll
        for (int j = 0; j < 8; ++j) acc[j] += __shfl_xor(acc[j], mk);
    }

    float inv = 1.f / (s + SM_EPS);
    unsigned int ov[4];
    #pragma unroll
    for (int j = 0; j < 4; ++j) {
        float v0 = acc[2 * j] * inv     + bias[cbase + 2 * j];
        float v1 = acc[2 * j + 1] * inv + bias[cbase + 2 * j + 1];
        v0 = v0 > 0.f ? v0 : __expf(v0) - 1.f;
        v1 = v1 > 0.f ? v1 : __expf(v1) - 1.f;
        ov[j] = (unsigned int)f2bf(v0) | ((unsigned int)f2bf(v1) << 16);
    }
    if (e8 == 0)
        *(uint4*)(hout + (size_t)n * 512 + cbase) = make_uint4(ov[0], ov[1], ov[2], ov[3]);
}

// ---------------- GEMM2 (bf16 MFMA) + fused attn2; hw2 stored bf16 ----------------

__global__ __launch_bounds__(256) void k_gemm2_mfma(const unsigned short* __restrict__ A,
                                                    const unsigned short* __restrict__ Bt,
                                                    const float* __restrict__ att_s,
                                                    const float* __restrict__ att_d,
                                                    unsigned short* __restrict__ O,
                                                    float* __restrict__ a_s, float* __restrict__ a_d,
                                                    int M) {
    const int K = 512;
    __shared__ unsigned short As[64 * 512];   // 64 KB
    __shared__ unsigned short Bs[32 * 512];   // 32 KB
    int t = threadIdx.x;
    int lane = t & 63;
    int w = t >> 6;
    int row0 = blockIdx.x * 64;
    int l15 = lane & 15, q = lane >> 4;

    #pragma unroll
    for (int i = 0; i < 16; ++i) {
        int r = w * 16 + i;
        gl_lds16(A + (size_t)(row0 + r) * K + ((lane ^ (r & 7)) << 3), &As[r * 512]);
    }
    #pragma unroll
    for (int i = 0; i < 8; ++i) {
        int r = w * 8 + i;
        gl_lds16(Bt + (size_t)r * K + ((lane ^ (r & 7)) << 3), &Bs[r * 512]);
    }
    __syncthreads();   // compiler drains vmcnt here

    floatx4 acc[2] = {};
    int ra = w * 16 + l15;
    int rb0 = l15, rb1 = 16 + l15;
    #pragma unroll
    for (int k0 = 0; k0 < K; k0 += 32) {
        int cc = (k0 >> 3) + q;   // 16B chunk index of this lane's fragment
        short8 af = *(const short8*)(&As[ra * 512 + ((cc ^ (ra & 7)) << 3)]);
        short8 b0 = *(const short8*)(&Bs[rb0 * 512 + ((cc ^ (rb0 & 7)) << 3)]);
        short8 b1 = *(const short8*)(&Bs[rb1 * 512 + ((cc ^ (rb1 & 7)) << 3)]);
        acc[0] = __builtin_amdgcn_mfma_f32_16x16x32_bf16(af, b0, acc[0], 0, 0, 0);
        acc[1] = __builtin_amdgcn_mfma_f32_16x16x32_bf16(af, b1, acc[1], 0, 0, 0);
    }

    float as_lo = att_s[l15], as_hi = att_s[16 + l15];
    float ad_lo = att_d[l15], ad_hi = att_d[16 + l15];
    #pragma unroll
    for (int p = 0; p < 4; ++p) {
        int r = row0 + w * 16 + q * 4 + p;
        bool ok = r < M;
        float v0 = acc[0][p], v1 = acc[1][p];
        if (ok) {
            O[(size_t)r * 32 + l15]      = f2bf(v0);
            O[(size_t)r * 32 + 16 + l15] = f2bf(v1);
        }
        float ds = v0 * as_lo + v1 * as_hi;
        float dd = v0 * ad_lo + v1 * ad_hi;
        #pragma unroll
        for (int mk = 1; mk <= 8; mk <<= 1) {
            ds += __shfl_xor(ds, mk);
            dd += __shfl_xor(dd, mk);
        }
        if (ok && l15 == 0) { a_s[r] = ds; a_d[r] = dd; }
    }
}

// ---------------- layer-2: 8-edge-parallel lane-private softmax+agg + log-softmax ----------------

__global__ __launch_bounds__(256) void k_l2(const unsigned short* __restrict__ hw2,
                                            const float* __restrict__ a_s,
                                            const float* __restrict__ a_d,
                                            const int* __restrict__ off,
                                            const int* __restrict__ src_s,
                                            const float* __restrict__ bias,
                                            float* __restrict__ outp, int N) {
    int wid = threadIdx.x >> 6, lane = threadIdx.x & 63;
    int n = blockIdx.x * 4 + wid;
    if (n >= N) return;
    int p0 = off[n], p1 = off[n + 1];
    float adv = a_d[n];
    int e8 = lane >> 3;                 // edge slot 0..7
    int li = lane & 7;                  // channel group: channels li*4 .. li*4+3
    const int cbase = li * 4;

    float acc[4] = {};
    float s = 0.f;
    int p = p0;
    for (; p + 16 <= p1; p += 16) {     // 2x unrolled 8-edge groups (2 gathers in flight)
        int sA = src_s[p + e8];
        int sB = src_s[p + 8 + e8];
        const uint2 uA = *(const uint2*)(hw2 + (size_t)sA * 32 + cbase);
        const uint2 uB = *(const uint2*)(hw2 + (size_t)sB * 32 + cbase);
        float eA = a_s[sA] + adv; eA = eA > 0.f ? eA : NEG_SLOPE * eA;
        float eB = a_s[sB] + adv; eB = eB > 0.f ? eB : NEG_SLOPE * eB;
        float wA = __expf(eA);
        float wB = __expf(eB);
        s += wA + wB;
        acc[0] = fmaf(wA, bflo(uA.x), acc[0]); acc[1] = fmaf(wA, bfhi(uA.x), acc[1]);
        acc[2] = fmaf(wA, bflo(uA.y), acc[2]); acc[3] = fmaf(wA, bfhi(uA.y), acc[3]);
        acc[0] = fmaf(wB, bflo(uB.x), acc[0]); acc[1] = fmaf(wB, bfhi(uB.x), acc[1]);
        acc[2] = fmaf(wB, bflo(uB.y), acc[2]); acc[3] = fmaf(wB, bfhi(uB.y), acc[3]);
    }
    for (; p + 8 <= p1; p += 8) {
        int sA = src_s[p + e8];
        const uint2 uA = *(const uint2*)(hw2 + (size_t)sA * 32 + cbase);
        float eA = a_s[sA] + adv; eA = eA > 0.f ? eA : NEG_SLOPE * eA;
        float wA = __expf(eA);
        s += wA;
        acc[0] = fmaf(wA, bflo(uA.x), acc[0]); acc[1] = fmaf(wA, bfhi(uA.x), acc[1]);
        acc[2] = fmaf(wA, bflo(uA.y), acc[2]); acc[3] = fmaf(wA, bfhi(uA.y), acc[3]);
    }
    if (p < p1) {                       // masked tail, <=7 edges
        int nb = p1 - p;
        bool val = e8 < nb;
        int sA = src_s[val ? p + e8 : p];
        const uint2 uA = *(const uint2*)(hw2 + (size_t)sA * 32 + cbase);
        float eA = a_s[sA] + adv; eA = eA > 0.f ? eA : NEG_SLOPE * eA;
        float wA = val ? __expf(eA) : 0.f;
        s += wA;
        acc[0] = fmaf(wA, bflo(uA.x), acc[0]); acc[1] = fmaf(wA, bfhi(uA.x), acc[1]);
        acc[2] = fmaf(wA, bflo(uA.y), acc[2]); acc[3] = fmaf(wA, bfhi(uA.y), acc[3]);
    }

    // reduce across the 8 edge slots (lane stride 8)
    #pragma unroll
    for (int mk = 8; mk <= 32; mk <<= 1) {
        s += __shfl_xor(s, mk);
        #pragma unroll
        for (int j = 0; j < 4; ++j) acc[j] += __shfl_xor(acc[j], mk);
    }

    float inv = 1.f / (s + SM_EPS);
    float v[4];
    #pragma unroll
    for (int j = 0; j < 4; ++j) v[j] = acc[j] * inv + bias[cbase + j];

    // log-softmax over 32 channels spread across li=0..7 (4 each)
    float mx = fmaxf(fmaxf(v[0], v[1]), fmaxf(v[2], v[3]));
    mx = fmaxf(mx, __shfl_xor(mx, 1));
    mx = fmaxf(mx, __shfl_xor(mx, 2));
    mx = fmaxf(mx, __shfl_xor(mx, 4));
    float sum = 0.f;
    #pragma unroll
    for (int j = 0; j < 4; ++j) sum += __expf(v[j] - mx);
    sum += __shfl_xor(sum, 1);
    sum += __shfl_xor(sum, 2);
    sum += __shfl_xor(sum, 4);
    float lse = __logf(sum);
    if (e8 == 0) {
        float4 o = make_float4(v[0] - mx - lse, v[1] - mx - lse,
                               v[2] - mx - lse, v[3] - mx - lse);
        *(float4*)(outp + (size_t)n * 32 + cbase) = o;
    }
}

// ---------------- launch ----------------

extern "C" void kernel_launch(void* const* d_in, const int* in_sizes, int n_in,
                              void* d_out, int out_size, void* d_ws, size_t ws_size,
                              hipStream_t stream) {
    const float* x   = (const float*)d_in[0];
    const int*   ei  = (const int*)d_in[1];
    const float* W1  = (const float*)d_in[2];
    const float* as1 = (const float*)d_in[3];
    const float* ad1 = (const float*)d_in[4];
    const float* b1  = (const float*)d_in[5];
    const float* W2  = (const float*)d_in[6];
    const float* as2 = (const float*)d_in[7];
    const float* ad2 = (const float*)d_in[8];
    const float* b2  = (const float*)d_in[9];
    float* out = (float*)d_out;

    const int F = 512;
    const int N = in_sizes[0] / F;     // 20000
    const int E = in_sizes[1] / 2;     // 320000
    const int Ep = E + N;              // with self-loops
    const int* srcA = ei;
    const int* dstA = ei + E;

    char* w = (char*)d_ws;
    auto alloc = [&](size_t b) -> void* {
        void* p = (void*)w;
        w += (b + 255) & ~(size_t)255;
        return p;
    };
    unsigned short* xbf  = (unsigned short*)alloc((size_t)N * 512 * 2);
    unsigned short* w1t  = (unsigned short*)alloc((size_t)512 * 512 * 2);
    unsigned short* w2bt = (unsigned short*)alloc((size_t)32 * 512 * 2);
    unsigned short* xw1  = (unsigned short*)alloc((size_t)N * 512 * 2);
    unsigned short* hbuf = (unsigned short*)alloc((size_t)N * 512 * 2);   // bf16 h
    float* a_s1 = (float*)alloc((size_t)N * 8 * 4);   // head-major [8][N]
    float* a_d1 = (float*)alloc((size_t)N * 8 * 4);   // head-major [8][N]
    unsigned short* hw2 = (unsigned short*)alloc((size_t)N * 32 * 2);    // bf16 hw2
    float* a_s2 = (float*)alloc((size_t)N * 4);
    float* a_d2 = (float*)alloc((size_t)N * 4);
    int* deg    = (int*)alloc((size_t)N * 4);
    int* done   = (int*)alloc(256);                   // scan flag, zeroed with deg
    int* incl   = (int*)alloc((size_t)N * 4);
    int* part   = (int*)alloc(256 * 4);
    int* off    = (int*)alloc((size_t)(N + 1) * 4);
    int* cursor = (int*)alloc((size_t)N * 4);
    int* src_s  = (int*)alloc((size_t)Ep * 4);
    (void)incl;

    int egrid = (Ep + 255) / 256;
    int sgrid = (N + 255) / 256;
    int ngrid4 = (N + 3) / 4;
    int nblk_x = (N * 512 / 4) / 256;           // 10000
    int nblk_w2 = (32 * 512 + 255) / 256;       // 64

    // zero deg + done in one memset (deg region is 256B-padded; done follows)
    hipMemsetAsync(deg, 0, (((size_t)N * 4 + 255) & ~(size_t)255) + 256, stream);

    // fused prep: deg | x cast | W1t | W2t
    k_prep<<<egrid + nblk_x + 256 + nblk_w2, 256, 0, stream>>>(
        x, xbf, W1, w1t, W2, w2bt, dstA, E, Ep, deg, egrid, nblk_x);

    // CSR (shared by both layers): fused single-pass scan + scatter
    k_scan_fused<<<sgrid, 256, 0, stream>>>(deg, part, done, off, cursor, N, sgrid);
    k_scatter<<<egrid, 256, 0, stream>>>(srcA, dstA, E, Ep, cursor, src_s);

    // layer 1
    {
        dim3 g1((N + 63) / 64, 512 / 128);       // 313 x 4
        k_gemm1_mfma<<<g1, 256, 0, stream>>>(xbf, w1t, as1, ad1, xw1, a_s1, a_d1, N);
    }
    {
        int nblk_l1 = ((N + 3) / 4) * 8;         // 4 nodes/block x 8 heads
        k_l1<<<nblk_l1, 256, 0, stream>>>(xw1, a_s1, a_d1, off, src_s, b1, hbuf, N);
    }

    // layer 2
    k_gemm2_mfma<<<(N + 63) / 64, 256, 0, stream>>>(hbuf, w2bt, as2, ad2, hw2, a_s2, a_d2, N);
    k_l2<<<ngrid4, 256, 0, stream>>>(hw2, a_s2, a_d2, off, src_s, b2, out, N);
}

// Round 6
// 222.055 us; speedup vs baseline: 1.1358x; 1.1358x over previous
//
#include <hip/hip_runtime.h>
#include <math.h>

#define NEG_SLOPE 0.2f
#define SM_EPS 1e-16f

typedef short short8 __attribute__((ext_vector_type(8)));
typedef float floatx4 __attribute__((ext_vector_type(4)));

// ---------------- helpers ----------------

__device__ inline unsigned short f2bf(float x) {
    unsigned int u = __float_as_uint(x);
    unsigned int r = (u + 0x7FFFu + ((u >> 16) & 1u)) >> 16;
    return (unsigned short)r;
}

__device__ inline float bf2f(unsigned short h) {
    return __uint_as_float(((unsigned int)h) << 16);
}

__device__ inline float bflo(unsigned int u) { return __uint_as_float(u << 16); }
__device__ inline float bfhi(unsigned int u) { return __uint_as_float(u & 0xFFFF0000u); }

// packed-pair helpers: give the compiler float2-shaped ops so it can form
// v_pk_fma_f32 (VOP3P, 2 FMAs/inst on CDNA).
__device__ inline float2 bf2x2(unsigned int u) {
    return make_float2(__uint_as_float(u << 16), __uint_as_float(u & 0xFFFF0000u));
}
__device__ inline float2 pk_fma(float w, float2 v, float2 a) {
    return make_float2(fmaf(w, v.x, a.x), fmaf(w, v.y, a.y));
}

// async global->LDS 16B copy: LDS dst = wave-uniform base + lane*16
__device__ __forceinline__ void gl_lds16(const unsigned short* g, unsigned short* l) {
    __builtin_amdgcn_global_load_lds(
        (const __attribute__((address_space(1))) unsigned int*)(g),
        (__attribute__((address_space(3))) unsigned int*)(l), 16, 0, 0);
}

__device__ inline void get_edge(const int* __restrict__ srcA, const int* __restrict__ dstA,
                                int e, int E, int& s, int& d) {
    if (e < E) { s = srcA[e]; d = dstA[e]; }
    else { s = e - E; d = e - E; }   // self-loops appended after real edges
}

// ---------------- fused prep: deg histogram | x->bf16 | W1t | W2t ----------------

__global__ __launch_bounds__(256) void k_prep(const float* __restrict__ x,
                                              unsigned short* __restrict__ xb,
                                              const float* __restrict__ W1,
                                              unsigned short* __restrict__ w1t,
                                              const float* __restrict__ W2,
                                              unsigned short* __restrict__ w2bt,
                                              const int* __restrict__ dstA,
                                              int E, int Ep,
                                              int* __restrict__ deg,
                                              int nblk_deg, int nblk_x) {
    __shared__ float tile[32][33];
    int bx = blockIdx.x;
    int t = threadIdx.x;
    if (bx < nblk_deg) {
        int e = bx * 256 + t;
        if (e < Ep) {
            int d = (e < E) ? dstA[e] : (e - E);
            atomicAdd(&deg[d], 1);
        }
    } else if (bx < nblk_deg + nblk_x) {
        int i = ((bx - nblk_deg) * 256 + t) * 4;
        float4 v = *(const float4*)(x + i);
        ushort4 o;
        o.x = f2bf(v.x); o.y = f2bf(v.y); o.z = f2bf(v.z); o.w = f2bf(v.w);
        *(ushort4*)(xb + i) = o;
    } else if (bx < nblk_deg + nblk_x + 256) {
        int b = bx - nblk_deg - nblk_x;          // 0..255
        int kb = (b & 15) * 32;                  // k base
        int nb = (b >> 4) * 32;                  // n base
        int tx = t & 31, ty = t >> 5;            // 32x8
        #pragma unroll
        for (int i = 0; i < 32; i += 8)
            tile[ty + i][tx] = W1[(size_t)(kb + ty + i) * 512 + nb + tx];
        __syncthreads();
        #pragma unroll
        for (int i = 0; i < 32; i += 8)
            w1t[(size_t)(nb + ty + i) * 512 + kb + tx] = f2bf(tile[tx][ty + i]);
    } else {
        int i = (bx - nblk_deg - nblk_x - 256) * 256 + t;   // 0..16383
        int c = i >> 9, k = i & 511;
        w2bt[i] = f2bf(W2[k * 32 + c]);
    }
}

// ---------------- CSR build: fused single-pass scan ----------------
// 79 blocks << 256 CUs -> all co-resident -> device-scope flag barrier is safe.

__global__ __launch_bounds__(256) void k_scan_fused(const int* __restrict__ deg,
                                                    int* __restrict__ part,
                                                    int* __restrict__ done,
                                                    int* __restrict__ off,
                                                    int* __restrict__ cursor,
                                                    int N, int nblk) {
    __shared__ int sm[256];
    int bx = blockIdx.x, t = threadIdx.x;
    int i = bx * 256 + t;
    int v = (i < N) ? deg[i] : 0;
    sm[t] = v; __syncthreads();
    for (int o = 1; o < 256; o <<= 1) {
        int x = (t >= o) ? sm[t - o] : 0;
        __syncthreads();
        sm[t] += x;
        __syncthreads();
    }
    int incl_v = sm[t];
    if (t == 255) {
        part[bx] = sm[255];
        __threadfence();              // publish part before flag
        atomicAdd(done, 1);
    }
    if (t == 0) {
        while (atomicAdd(done, 0) < nblk) { }   // spin: all parts published
        __threadfence();
    }
    __syncthreads();
    int partial = 0;
    for (int j = t; j < bx; j += 256) partial += atomicAdd(&part[j], 0);
    sm[t] = partial; __syncthreads();
    for (int o = 128; o > 0; o >>= 1) {
        if (t < o) sm[t] += sm[t + o];
        __syncthreads();
    }
    int base = sm[0];
    if (i < N) {
        int vv = incl_v + base;       // inclusive scan value
        off[i + 1] = vv;
        cursor[i] = vv - v;
        if (i == 0) off[0] = 0;
    }
}

__global__ __launch_bounds__(256) void k_scatter(const int* __restrict__ srcA, const int* __restrict__ dstA,
                                                 int E, int Ep, int* __restrict__ cursor,
                                                 int* __restrict__ src_s) {
    int e = blockIdx.x * 256 + threadIdx.x;
    if (e >= Ep) return;
    int s, d; get_edge(srcA, dstA, e, E, s, d);
    int p = atomicAdd(&cursor[d], 1);
    src_s[p] = s;
}

// ---------------- GEMM1 (bf16 MFMA) + fused attn1 ----------------
// v5: BM=64, BN=128, BK=32, 4 waves (wave = 32x64, acc[2][4] = 32 AGPR).
// counted vmcnt(3) pipeline, both-sides XOR swizzle.
// attn dots HEAD-MAJOR: a_sd[h*N + r].

__global__ __launch_bounds__(256, 4) void k_gemm1_mfma(const unsigned short* __restrict__ A,
                                                       const unsigned short* __restrict__ Bt,
                                                       const float* __restrict__ att_s,
                                                       const float* __restrict__ att_d,
                                                       unsigned short* __restrict__ C,
                                                       float* __restrict__ a_sd,
                                                       float* __restrict__ a_dd, int M) {
    const int K = 512;
    __shared__ unsigned short As[2][64 * 32];    // 2 x 4 KB
    __shared__ unsigned short Bs[2][128 * 32];   // 2 x 8 KB
    int t = threadIdx.x;
    int lane = t & 63;
    int w = t >> 6;                  // 0..3
    int row0 = blockIdx.x * 64;
    int col0 = blockIdx.y * 128;
    int wm = (w >> 1) * 32, wn = (w & 1) * 64;
    int l15 = lane & 15, q = lane >> 4;

    int srl = lane >> 2;                              // row within 16-group
    int sgc = ((lane & 3) ^ ((lane >> 3) & 3)) * 8;   // swizzled src chunk (elements)

    floatx4 acc[2][4] = {};

    auto STAGE = [&](int buf, int k0) {
        gl_lds16(A  + (size_t)(row0 + w * 16 + srl) * K + k0 + sgc, &As[buf][(w * 16) * 32]);
        gl_lds16(Bt + (size_t)(col0 + w * 32 + srl) * K + k0 + sgc, &Bs[buf][(w * 32) * 32]);
        gl_lds16(Bt + (size_t)(col0 + w * 32 + 16 + srl) * K + k0 + sgc, &Bs[buf][(w * 32 + 16) * 32]);
    };

    STAGE(0, 0);
    asm volatile("s_waitcnt vmcnt(0)" ::: "memory");
    __builtin_amdgcn_s_barrier();

    int swz = (l15 >> 1) & 3;        // (row>>1)&3 for row = {wm|wn} + i*16 + l15
    int buf = 0;
    for (int k0 = 0; k0 < K; k0 += 32) {
        if (k0 + 32 < K) {
            STAGE(buf ^ 1, k0 + 32);                       // 3 loads in flight across barrier
            asm volatile("s_waitcnt vmcnt(3)" ::: "memory");
        } else {
            asm volatile("s_waitcnt vmcnt(0)" ::: "memory");
        }
        __builtin_amdgcn_s_barrier();
        __builtin_amdgcn_sched_barrier(0);
        short8 af[2], bfr[4];
        int sw = (q ^ swz) << 3;     // swizzled 16B chunk -> element offset
        #pragma unroll
        for (int i = 0; i < 2; ++i)
            af[i] = *(const short8*)(&As[buf][(wm + i * 16 + l15) * 32 + sw]);
        #pragma unroll
        for (int j = 0; j < 4; ++j)
            bfr[j] = *(const short8*)(&Bs[buf][(wn + j * 16 + l15) * 32 + sw]);
        #pragma unroll
        for (int i = 0; i < 2; ++i)
            #pragma unroll
            for (int j = 0; j < 4; ++j)
                acc[i][j] = __builtin_amdgcn_mfma_f32_16x16x32_bf16(af[i], bfr[j], acc[i][j], 0, 0, 0);
        asm volatile("s_waitcnt lgkmcnt(0)" ::: "memory");
        __builtin_amdgcn_sched_barrier(0);
        __builtin_amdgcn_s_barrier();
        buf ^= 1;
    }

    #pragma unroll
    for (int i = 0; i < 2; ++i) {
        #pragma unroll
        for (int p = 0; p < 4; ++p) {
            int r = row0 + wm + i * 16 + q * 4 + p;
            if (r < M) {
                #pragma unroll
                for (int j = 0; j < 4; ++j) {
                    int c = col0 + wn + j * 16 + l15;
                    C[(size_t)r * 512 + c] = f2bf(acc[i][j][p]);
                }
            }
        }
    }

    int hh = blockIdx.y * 2 + (w & 1);   // wave's wn half = one full 64-chan head
    float asr[4], adr[4];
    #pragma unroll
    for (int j = 0; j < 4; ++j) {
        asr[j] = att_s[hh * 64 + j * 16 + l15];
        adr[j] = att_d[hh * 64 + j * 16 + l15];
    }
    #pragma unroll
    for (int i = 0; i < 2; ++i) {
        #pragma unroll
        for (int p = 0; p < 4; ++p) {
            float ds = 0.f, dd = 0.f;
            #pragma unroll
            for (int j = 0; j < 4; ++j) {
                ds = fmaf(acc[i][j][p], asr[j], ds);
                dd = fmaf(acc[i][j][p], adr[j], dd);
            }
            #pragma unroll
            for (int mk = 1; mk <= 8; mk <<= 1) {
                ds += __shfl_xor(ds, mk);
                dd += __shfl_xor(dd, mk);
            }
            int r = row0 + wm + i * 16 + q * 4 + p;
            if (l15 == 0 && r < M) {
                a_sd[(size_t)hh * M + r] = ds;
                a_dd[(size_t)hh * M + r] = dd;
            }
        }
    }
}

// ---------------- layer-1 (v2 revert + float2 packed accumulate) ----------------
// Wave = 8 nodes x 1 head; lane = (node-sub = lane>>3, chan-sub li = lane&7).
// Lane-private edge walk: NO cross-lane reduction (round-5 lesson: the v3
// wave-per-node layout's 27-bpermute reduce + per-wave overhead cost 2x).
// head = blockIdx.x & 7 -> XCD affinity. Quad unroll + next-quad src prefetch.
// acc held as float2[4]: unpack uint -> float2, pk_fma shape so the compiler
// can emit v_pk_fma_f32 (2 FMAs/inst).

__global__ __launch_bounds__(256) void k_l1(const unsigned short* __restrict__ xw,
                                            const float* __restrict__ a_s,
                                            const float* __restrict__ a_d,
                                            const int* __restrict__ off,
                                            const int* __restrict__ src_s,
                                            const float* __restrict__ bias,
                                            unsigned short* __restrict__ hout, int N) {
    int wid = threadIdx.x >> 6, lane = threadIdx.x & 63;
    int h = blockIdx.x & 7;
    int n = (blockIdx.x >> 3) * 32 + wid * 8 + (lane >> 3);
    int li = lane & 7;
    if (n >= N) return;
    int p0 = off[n], p1 = off[n + 1];
    const float* ash = a_s + (size_t)h * N;
    float adv = a_d[(size_t)h * N + n];
    const size_t cbase = (size_t)h * 64 + (size_t)li * 8;

    float2 acc[4] = {};
    float s = 0.f;
    int p = p0;
    if (p + 4 <= p1) {
        int s0 = src_s[p], s1 = src_s[p + 1], s2 = src_s[p + 2], s3 = src_s[p + 3];
        while (true) {
            const uint4 u0 = *(const uint4*)(xw + (size_t)s0 * 512 + cbase);
            const uint4 u1 = *(const uint4*)(xw + (size_t)s1 * 512 + cbase);
            const uint4 u2 = *(const uint4*)(xw + (size_t)s2 * 512 + cbase);
            const uint4 u3 = *(const uint4*)(xw + (size_t)s3 * 512 + cbase);
            float e0 = ash[s0] + adv; e0 = e0 > 0.f ? e0 : NEG_SLOPE * e0;
            float e1 = ash[s1] + adv; e1 = e1 > 0.f ? e1 : NEG_SLOPE * e1;
            float e2 = ash[s2] + adv; e2 = e2 > 0.f ? e2 : NEG_SLOPE * e2;
            float e3 = ash[s3] + adv; e3 = e3 > 0.f ? e3 : NEG_SLOPE * e3;
            int np = p + 4;
            bool more = (np + 4 <= p1);
            int t0 = 0, t1 = 0, t2 = 0, t3 = 0;
            if (more) {                        // preload next quad's srcs early
                t0 = src_s[np]; t1 = src_s[np + 1];
                t2 = src_s[np + 2]; t3 = src_s[np + 3];
            }
            float w0 = __expf(e0);
            float w1 = __expf(e1);
            float w2 = __expf(e2);
            float w3 = __expf(e3);
            s += (w0 + w1) + (w2 + w3);
            acc[0] = pk_fma(w0, bf2x2(u0.x), acc[0]);
            acc[1] = pk_fma(w0, bf2x2(u0.y), acc[1]);
            acc[2] = pk_fma(w0, bf2x2(u0.z), acc[2]);
            acc[3] = pk_fma(w0, bf2x2(u0.w), acc[3]);
            acc[0] = pk_fma(w1, bf2x2(u1.x), acc[0]);
            acc[1] = pk_fma(w1, bf2x2(u1.y), acc[1]);
            acc[2] = pk_fma(w1, bf2x2(u1.z), acc[2]);
            acc[3] = pk_fma(w1, bf2x2(u1.w), acc[3]);
            acc[0] = pk_fma(w2, bf2x2(u2.x), acc[0]);
            acc[1] = pk_fma(w2, bf2x2(u2.y), acc[1]);
            acc[2] = pk_fma(w2, bf2x2(u2.z), acc[2]);
            acc[3] = pk_fma(w2, bf2x2(u2.w), acc[3]);
            acc[0] = pk_fma(w3, bf2x2(u3.x), acc[0]);
            acc[1] = pk_fma(w3, bf2x2(u3.y), acc[1]);
            acc[2] = pk_fma(w3, bf2x2(u3.z), acc[2]);
            acc[3] = pk_fma(w3, bf2x2(u3.w), acc[3]);
            p = np;
            if (!more) break;
            s0 = t0; s1 = t1; s2 = t2; s3 = t3;
        }
    }
    for (; p < p1; ++p) {
        int s0 = src_s[p];
        const uint4 u0 = *(const uint4*)(xw + (size_t)s0 * 512 + cbase);
        float e0 = ash[s0] + adv; e0 = e0 > 0.f ? e0 : NEG_SLOPE * e0;
        float w0 = __expf(e0);
        s += w0;
        acc[0] = pk_fma(w0, bf2x2(u0.x), acc[0]);
        acc[1] = pk_fma(w0, bf2x2(u0.y), acc[1]);
        acc[2] = pk_fma(w0, bf2x2(u0.z), acc[2]);
        acc[3] = pk_fma(w0, bf2x2(u0.w), acc[3]);
    }

    float inv = 1.f / (s + SM_EPS);
    unsigned int ov[4];
    #pragma unroll
    for (int j = 0; j < 4; ++j) {
        float v0 = acc[j].x * inv + bias[cbase + 2 * j];
        float v1 = acc[j].y * inv + bias[cbase + 2 * j + 1];
        v0 = v0 > 0.f ? v0 : __expf(v0) - 1.f;
        v1 = v1 > 0.f ? v1 : __expf(v1) - 1.f;
        ov[j] = (unsigned int)f2bf(v0) | ((unsigned int)f2bf(v1) << 16);
    }
    *(uint4*)(hout + (size_t)n * 512 + cbase) = make_uint4(ov[0], ov[1], ov[2], ov[3]);
}

// ---------------- GEMM2 (bf16 MFMA) + fused attn2; hw2 stored bf16 ----------------

__global__ __launch_bounds__(256) void k_gemm2_mfma(const unsigned short* __restrict__ A,
                                                    const unsigned short* __restrict__ Bt,
                                                    const float* __restrict__ att_s,
                                                    const float* __restrict__ att_d,
                                                    unsigned short* __restrict__ O,
                                                    float* __restrict__ a_s, float* __restrict__ a_d,
                                                    int M) {
    const int K = 512;
    __shared__ unsigned short As[64 * 512];   // 64 KB
    __shared__ unsigned short Bs[32 * 512];   // 32 KB
    int t = threadIdx.x;
    int lane = t & 63;
    int w = t >> 6;
    int row0 = blockIdx.x * 64;
    int l15 = lane & 15, q = lane >> 4;

    #pragma unroll
    for (int i = 0; i < 16; ++i) {
        int r = w * 16 + i;
        gl_lds16(A + (size_t)(row0 + r) * K + ((lane ^ (r & 7)) << 3), &As[r * 512]);
    }
    #pragma unroll
    for (int i = 0; i < 8; ++i) {
        int r = w * 8 + i;
        gl_lds16(Bt + (size_t)r * K + ((lane ^ (r & 7)) << 3), &Bs[r * 512]);
    }
    __syncthreads();   // compiler drains vmcnt here

    floatx4 acc[2] = {};
    int ra = w * 16 + l15;
    int rb0 = l15, rb1 = 16 + l15;
    #pragma unroll
    for (int k0 = 0; k0 < K; k0 += 32) {
        int cc = (k0 >> 3) + q;   // 16B chunk index of this lane's fragment
        short8 af = *(const short8*)(&As[ra * 512 + ((cc ^ (ra & 7)) << 3)]);
        short8 b0 = *(const short8*)(&Bs[rb0 * 512 + ((cc ^ (rb0 & 7)) << 3)]);
        short8 b1 = *(const short8*)(&Bs[rb1 * 512 + ((cc ^ (rb1 & 7)) << 3)]);
        acc[0] = __builtin_amdgcn_mfma_f32_16x16x32_bf16(af, b0, acc[0], 0, 0, 0);
        acc[1] = __builtin_amdgcn_mfma_f32_16x16x32_bf16(af, b1, acc[1], 0, 0, 0);
    }

    float as_lo = att_s[l15], as_hi = att_s[16 + l15];
    float ad_lo = att_d[l15], ad_hi = att_d[16 + l15];
    #pragma unroll
    for (int p = 0; p < 4; ++p) {
        int r = row0 + w * 16 + q * 4 + p;
        bool ok = r < M;
        float v0 = acc[0][p], v1 = acc[1][p];
        if (ok) {
            O[(size_t)r * 32 + l15]      = f2bf(v0);
            O[(size_t)r * 32 + 16 + l15] = f2bf(v1);
        }
        float ds = v0 * as_lo + v1 * as_hi;
        float dd = v0 * ad_lo + v1 * ad_hi;
        #pragma unroll
        for (int mk = 1; mk <= 8; mk <<= 1) {
            ds += __shfl_xor(ds, mk);
            dd += __shfl_xor(dd, mk);
        }
        if (ok && l15 == 0) { a_s[r] = ds; a_d[r] = dd; }
    }
}

// ---------------- layer-2: 8-edge-parallel lane-private softmax+agg + log-softmax ----------------

__global__ __launch_bounds__(256) void k_l2(const unsigned short* __restrict__ hw2,
                                            const float* __restrict__ a_s,
                                            const float* __restrict__ a_d,
                                            const int* __restrict__ off,
                                            const int* __restrict__ src_s,
                                            const float* __restrict__ bias,
                                            float* __restrict__ outp, int N) {
    int wid = threadIdx.x >> 6, lane = threadIdx.x & 63;
    int n = blockIdx.x * 4 + wid;
    if (n >= N) return;
    int p0 = off[n], p1 = off[n + 1];
    float adv = a_d[n];
    int e8 = lane >> 3;                 // edge slot 0..7
    int li = lane & 7;                  // channel group: channels li*4 .. li*4+3
    const int cbase = li * 4;

    float acc[4] = {};
    float s = 0.f;
    int p = p0;
    for (; p + 16 <= p1; p += 16) {     // 2x unrolled 8-edge groups (2 gathers in flight)
        int sA = src_s[p + e8];
        int sB = src_s[p + 8 + e8];
        const uint2 uA = *(const uint2*)(hw2 + (size_t)sA * 32 + cbase);
        const uint2 uB = *(const uint2*)(hw2 + (size_t)sB * 32 + cbase);
        float eA = a_s[sA] + adv; eA = eA > 0.f ? eA : NEG_SLOPE * eA;
        float eB = a_s[sB] + adv; eB = eB > 0.f ? eB : NEG_SLOPE * eB;
        float wA = __expf(eA);
        float wB = __expf(eB);
        s += wA + wB;
        acc[0] = fmaf(wA, bflo(uA.x), acc[0]); acc[1] = fmaf(wA, bfhi(uA.x), acc[1]);
        acc[2] = fmaf(wA, bflo(uA.y), acc[2]); acc[3] = fmaf(wA, bfhi(uA.y), acc[3]);
        acc[0] = fmaf(wB, bflo(uB.x), acc[0]); acc[1] = fmaf(wB, bfhi(uB.x), acc[1]);
        acc[2] = fmaf(wB, bflo(uB.y), acc[2]); acc[3] = fmaf(wB, bfhi(uB.y), acc[3]);
    }
    for (; p + 8 <= p1; p += 8) {
        int sA = src_s[p + e8];
        const uint2 uA = *(const uint2*)(hw2 + (size_t)sA * 32 + cbase);
        float eA = a_s[sA] + adv; eA = eA > 0.f ? eA : NEG_SLOPE * eA;
        float wA = __expf(eA);
        s += wA;
        acc[0] = fmaf(wA, bflo(uA.x), acc[0]); acc[1] = fmaf(wA, bfhi(uA.x), acc[1]);
        acc[2] = fmaf(wA, bflo(uA.y), acc[2]); acc[3] = fmaf(wA, bfhi(uA.y), acc[3]);
    }
    if (p < p1) {                       // masked tail, <=7 edges
        int nb = p1 - p;
        bool val = e8 < nb;
        int sA = src_s[val ? p + e8 : p];
        const uint2 uA = *(const uint2*)(hw2 + (size_t)sA * 32 + cbase);
        float eA = a_s[sA] + adv; eA = eA > 0.f ? eA : NEG_SLOPE * eA;
        float wA = val ? __expf(eA) : 0.f;
        s += wA;
        acc[0] = fmaf(wA, bflo(uA.x), acc[0]); acc[1] = fmaf(wA, bfhi(uA.x), acc[1]);
        acc[2] = fmaf(wA, bflo(uA.y), acc[2]); acc[3] = fmaf(wA, bfhi(uA.y), acc[3]);
    }

    // reduce across the 8 edge slots (lane stride 8)
    #pragma unroll
    for (int mk = 8; mk <= 32; mk <<= 1) {
        s += __shfl_xor(s, mk);
        #pragma unroll
        for (int j = 0; j < 4; ++j) acc[j] += __shfl_xor(acc[j], mk);
    }

    float inv = 1.f / (s + SM_EPS);
    float v[4];
    #pragma unroll
    for (int j = 0; j < 4; ++j) v[j] = acc[j] * inv + bias[cbase + j];

    // log-softmax over 32 channels spread across li=0..7 (4 each)
    float mx = fmaxf(fmaxf(v[0], v[1]), fmaxf(v[2], v[3]));
    mx = fmaxf(mx, __shfl_xor(mx, 1));
    mx = fmaxf(mx, __shfl_xor(mx, 2));
    mx = fmaxf(mx, __shfl_xor(mx, 4));
    float sum = 0.f;
    #pragma unroll
    for (int j = 0; j < 4; ++j) sum += __expf(v[j] - mx);
    sum += __shfl_xor(sum, 1);
    sum += __shfl_xor(sum, 2);
    sum += __shfl_xor(sum, 4);
    float lse = __logf(sum);
    if (e8 == 0) {
        float4 o = make_float4(v[0] - mx - lse, v[1] - mx - lse,
                               v[2] - mx - lse, v[3] - mx - lse);
        *(float4*)(outp + (size_t)n * 32 + cbase) = o;
    }
}

// ---------------- launch ----------------

extern "C" void kernel_launch(void* const* d_in, const int* in_sizes, int n_in,
                              void* d_out, int out_size, void* d_ws, size_t ws_size,
                              hipStream_t stream) {
    const float* x   = (const float*)d_in[0];
    const int*   ei  = (const int*)d_in[1];
    const float* W1  = (const float*)d_in[2];
    const float* as1 = (const float*)d_in[3];
    const float* ad1 = (const float*)d_in[4];
    const float* b1  = (const float*)d_in[5];
    const float* W2  = (const float*)d_in[6];
    const float* as2 = (const float*)d_in[7];
    const float* ad2 = (const float*)d_in[8];
    const float* b2  = (const float*)d_in[9];
    float* out = (float*)d_out;

    const int F = 512;
    const int N = in_sizes[0] / F;     // 20000
    const int E = in_sizes[1] / 2;     // 320000
    const int Ep = E + N;              // with self-loops
    const int* srcA = ei;
    const int* dstA = ei + E;

    char* w = (char*)d_ws;
    auto alloc = [&](size_t b) -> void* {
        void* p = (void*)w;
        w += (b + 255) & ~(size_t)255;
        return p;
    };
    unsigned short* xbf  = (unsigned short*)alloc((size_t)N * 512 * 2);
    unsigned short* w1t  = (unsigned short*)alloc((size_t)512 * 512 * 2);
    unsigned short* w2bt = (unsigned short*)alloc((size_t)32 * 512 * 2);
    unsigned short* xw1  = (unsigned short*)alloc((size_t)N * 512 * 2);
    unsigned short* hbuf = (unsigned short*)alloc((size_t)N * 512 * 2);   // bf16 h
    float* a_s1 = (float*)alloc((size_t)N * 8 * 4);   // head-major [8][N]
    float* a_d1 = (float*)alloc((size_t)N * 8 * 4);   // head-major [8][N]
    unsigned short* hw2 = (unsigned short*)alloc((size_t)N * 32 * 2);    // bf16 hw2
    float* a_s2 = (float*)alloc((size_t)N * 4);
    float* a_d2 = (float*)alloc((size_t)N * 4);
    int* deg    = (int*)alloc((size_t)N * 4);
    int* done   = (int*)alloc(256);                   // scan flag, zeroed with deg
    int* incl   = (int*)alloc((size_t)N * 4);
    int* part   = (int*)alloc(256 * 4);
    int* off    = (int*)alloc((size_t)(N + 1) * 4);
    int* cursor = (int*)alloc((size_t)N * 4);
    int* src_s  = (int*)alloc((size_t)Ep * 4);
    (void)incl;

    int egrid = (Ep + 255) / 256;
    int sgrid = (N + 255) / 256;
    int ngrid4 = (N + 3) / 4;
    int nblk_x = (N * 512 / 4) / 256;           // 10000
    int nblk_w2 = (32 * 512 + 255) / 256;       // 64

    // zero deg + done in one memset (deg region is 256B-padded; done follows)
    hipMemsetAsync(deg, 0, (((size_t)N * 4 + 255) & ~(size_t)255) + 256, stream);

    // fused prep: deg | x cast | W1t | W2t
    k_prep<<<egrid + nblk_x + 256 + nblk_w2, 256, 0, stream>>>(
        x, xbf, W1, w1t, W2, w2bt, dstA, E, Ep, deg, egrid, nblk_x);

    // CSR (shared by both layers): fused single-pass scan + scatter
    k_scan_fused<<<sgrid, 256, 0, stream>>>(deg, part, done, off, cursor, N, sgrid);
    k_scatter<<<egrid, 256, 0, stream>>>(srcA, dstA, E, Ep, cursor, src_s);

    // layer 1
    {
        dim3 g1((N + 63) / 64, 512 / 128);       // 313 x 4
        k_gemm1_mfma<<<g1, 256, 0, stream>>>(xbf, w1t, as1, ad1, xw1, a_s1, a_d1, N);
    }
    {
        int ngrid32 = (N + 31) / 32;             // node groups of 32
        k_l1<<<ngrid32 * 8, 256, 0, stream>>>(xw1, a_s1, a_d1, off, src_s, b1, hbuf, N);
    }

    // layer 2
    k_gemm2_mfma<<<(N + 63) / 64, 256, 0, stream>>>(hbuf, w2bt, as2, ad2, hw2, a_s2, a_d2, N);
    k_l2<<<ngrid4, 256, 0, stream>>>(hw2, a_s2, a_d2, off, src_s, b2, out, N);
}